// Round 5
// baseline (1111.774 us; speedup 1.0000x reference)
//
#include <hip/hip_runtime.h>
#include <math.h>

// Problem constants (reference: H=256, N=32, S=256, R=1, CCH=32, L=2048, B=2)
#define LF   1025     // L/2+1

// ---- workspace layout (bytes) ---- (~151.3 MB total, unchanged)
#define OFF_TW   0
#define OFF_ZT   65536
#define OFF_KF   131072
#define OFF_PDF  67371008
#define OFF_DCT  84148224

__device__ __forceinline__ float2 cmulf(float2 a, float2 b){
    return make_float2(a.x*b.x - a.y*b.y, a.x*b.y + a.y*b.x);
}
// LDS padding: 1 extra float2 per 16 -> breaks power-of-2 bank aliasing of the
// Stockham scatter.
__device__ __forceinline__ int pidx(int i){ return i + (i >> 4); }

// ---------------- init: twiddles + bilinear nodes (fp64 once) ----------------
__global__ void initk(float2* __restrict__ TW, float4* __restrict__ ZT){
    int i = blockIdx.x*256 + threadIdx.x;
    if (i < 4096){
        double th = (-2.0*M_PI) * (double)i / 4096.0;
        TW[i] = make_float2((float)cos(th), (float)sin(th));
    }
    if (i < LF){
        double th = (-2.0*M_PI) * (double)i / 2048.0;
        double cr = cos(th), ci = sin(th);
        double ar = 1.0 + cr, ai = ci;              // 1+w
        double den = ar*ar + ai*ai;
        double nr = 1.0 - cr, ni = -ci;             // 1-w
        double zr = 2.0*(nr*ar + ni*ai)/den;        // z = 2(1-w)/(1+w)
        double zi = 2.0*(ni*ar - nr*ai)/den;
        ZT[i] = make_float4((float)zr, (float)zi, (float)(2.0*ar/den), (float)(-2.0*ai/den));
    }
}

// ---------------- dC (l, h, c) -> DCT (h*32+c, l) ----------------
__global__ void transpose_dC(const float* __restrict__ dC, float* __restrict__ DCT){
    __shared__ float tile[32][33];
    int hc0 = blockIdx.x*32;
    int l0  = blockIdx.y*32;
    int tx = threadIdx.x;
    for (int i = threadIdx.y; i < 32; i += 8)
        tile[i][tx] = dC[(size_t)(l0+i)*8192 + hc0 + tx];
    __syncthreads();
    for (int i = threadIdx.y; i < 32; i += 8)
        DCT[(size_t)(hc0+i)*2048 + l0 + tx] = tile[tx][i];
}

// ---------------- Cauchy + Woodbury -> k_f ---------------- (unchanged, passes)
__global__ __launch_bounds__(256) void cauchy_k(
                         const float* __restrict__ log_dt, const float* __restrict__ B_ri,
                         const float* __restrict__ P_ri, const float* __restrict__ C_ri,
                         const float* __restrict__ ivw, const float* __restrict__ wimag,
                         const float4* __restrict__ ZT, float2* __restrict__ KF)
{
    const int h  = blockIdx.y;
    const int c0 = blockIdx.z * 8;
    const int l  = blockIdx.x*256 + (int)threadIdx.x;
    __shared__ float wre[32], wim[32], bre[32], bim[32], ppre[32], ppim[32];
    __shared__ float cre[8][32], cim[8][32];
    __shared__ float dt_sh;
    if (threadIdx.x < 32){
        int n = threadIdx.x;
        float dt = expf(log_dt[h]);
        wre[n] = -expf(ivw[h*32+n]) * dt;
        wim[n] = wimag[h*32+n] * dt;
        bre[n] = B_ri[(h*32+n)*2+0];
        bim[n] = B_ri[(h*32+n)*2+1];
        ppre[n] = P_ri[(h*32+n)*2+0];
        ppim[n] = P_ri[(h*32+n)*2+1];
        if (n == 0) dt_sh = dt;
    }
    {
        int i = threadIdx.x;
        int cc = i >> 5, n = i & 31;
        size_t base = (((size_t)(c0+cc)*256 + h)*32 + n)*2;
        cre[cc][n] = C_ri[base+0];
        cim[cc][n] = C_ri[base+1];
    }
    __syncthreads();
    if (l >= LF) return;

    float4 zt = ZT[l];
    const float zx = zt.x, zy = zt.y;
    float r0x[9], r0y[9], r1x[9], r1y[9];
    #pragma unroll
    for (int j=0;j<9;++j){ r0x[j]=0.f; r0y[j]=0.f; r1x[j]=0.f; r1y[j]=0.f; }

    #pragma unroll 1
    for (int n=0; n<32; ++n){
        float wr = wre[n], wi = wim[n];
        float dx = zx - wr;
        float dy = zy - wi;
        float ey = zy + wi;
        float ip = 1.0f/(dx*dx + dy*dy);
        float im = 1.0f/(dx*dx + ey*ey);
        float cpx = dx*ip, cpy = -dy*ip;
        float cmx = dx*im, cmy = -ey*im;
        float br = bre[n], bi = bim[n];
        float t0x = br*cpx - bi*cpy, t0y = br*cpy + bi*cpx;
        float t1x = br*cmx + bi*cmy, t1y = br*cmy - bi*cmx;
        float pr = ppre[n], pi = ppim[n];
        float t2x = pr*cpx - pi*cpy, t2y = pr*cpy + pi*cpx;
        float t3x = pr*cmx + pi*cmy, t3y = pr*cmy - pi*cmx;
        float u0 = t0x+t1x, v0 = t1y-t0y, s0 = t0y+t1y, q0 = t0x-t1x;
        float u1 = t2x+t3x, v1 = t3y-t2y, s1 = t2y+t3y, q1 = t2x-t3x;
        #pragma unroll
        for (int j=0;j<8;++j){
            float a = cre[j][n], b = cim[j][n];
            r0x[j] = fmaf(a,u0, fmaf(b,v0, r0x[j]));
            r0y[j] = fmaf(a,s0, fmaf(b,q0, r0y[j]));
            r1x[j] = fmaf(a,u1, fmaf(b,v1, r1x[j]));
            r1y[j] = fmaf(a,s1, fmaf(b,q1, r1y[j]));
        }
        r0x[8] = fmaf(pr,u0, fmaf(-pi,v0, r0x[8]));
        r0y[8] = fmaf(pr,s0, fmaf(-pi,q0, r0y[8]));
        r1x[8] = fmaf(pr,u1, fmaf(-pi,v1, r1x[8]));
        r1y[8] = fmaf(pr,s1, fmaf(-pi,q1, r1y[8]));
    }

    float dt = dt_sh;
    #pragma unroll
    for (int j=0;j<9;++j){ r0x[j]*=dt; r0y[j]*=dt; r1x[j]*=dt; r1y[j]*=dt; }
    float drr = 1.0f + r1x[8], dii = r1y[8];
    float idn = 1.0f/(drr*drr + dii*dii);
    float gx = (r0x[8]*drr + r0y[8]*dii)*idn;
    float gy = (r0y[8]*drr - r0x[8]*dii)*idn;
    float tfx = zt.z, tfy = zt.w;
    #pragma unroll
    for (int j=0;j<8;++j){
        float kr = r0x[j] - (gx*r1x[j] - gy*r1y[j]);
        float ki = r0y[j] - (gx*r1y[j] + gy*r1x[j]);
        KF[((size_t)((c0+j)*256+h))*1026 + l] = make_float2(kr*tfx - ki*tfy, kr*tfy + ki*tfx);
    }
}

// ---------------- Stockham stages, radix-8 / radix-4, padded LDS ----------------
template<int N, int T, bool INV>
__device__ __forceinline__ void r8stage(const float2* __restrict__ in, float2* __restrict__ out,
                                        const float2* __restrict__ tw, int Ns){
    __syncthreads();
    #pragma unroll
    for (int base = 0; base < N/8; base += T){
        int j = base + (int)threadIdx.x;
        int jm = j & (Ns-1);
        int st = jm * (4096/(Ns*8));
        float2 v[8];
        #pragma unroll
        for (int m=0;m<8;++m) v[m] = in[pidx(j + m*(N/8))];
        #pragma unroll
        for (int m=1;m<8;++m){
            float2 w = tw[m*st];
            if (INV) w.y = -w.y;
            v[m] = cmulf(v[m], w);
        }
        float2 e0,e1,e2,e3,o0,o1,o2,o3;
        {   // DFT4 of v0,v2,v4,v6
            float t0x=v[0].x+v[4].x, t0y=v[0].y+v[4].y;
            float t1x=v[0].x-v[4].x, t1y=v[0].y-v[4].y;
            float t2x=v[2].x+v[6].x, t2y=v[2].y+v[6].y;
            float t3x=v[2].x-v[6].x, t3y=v[2].y-v[6].y;
            e0 = make_float2(t0x+t2x, t0y+t2y);
            e2 = make_float2(t0x-t2x, t0y-t2y);
            if (!INV){ e1 = make_float2(t1x+t3y, t1y-t3x); e3 = make_float2(t1x-t3y, t1y+t3x); }
            else     { e1 = make_float2(t1x-t3y, t1y+t3x); e3 = make_float2(t1x+t3y, t1y-t3x); }
        }
        {   // DFT4 of v1,v3,v5,v7
            float t0x=v[1].x+v[5].x, t0y=v[1].y+v[5].y;
            float t1x=v[1].x-v[5].x, t1y=v[1].y-v[5].y;
            float t2x=v[3].x+v[7].x, t2y=v[3].y+v[7].y;
            float t3x=v[3].x-v[7].x, t3y=v[3].y-v[7].y;
            o0 = make_float2(t0x+t2x, t0y+t2y);
            o2 = make_float2(t0x-t2x, t0y-t2y);
            if (!INV){ o1 = make_float2(t1x+t3y, t1y-t3x); o3 = make_float2(t1x-t3y, t1y+t3x); }
            else     { o1 = make_float2(t1x-t3y, t1y+t3x); o3 = make_float2(t1x+t3y, t1y-t3x); }
        }
        const float RC = 0.70710678118654752f;
        float2 w1o1, w2o2, w3o3;
        if (!INV){
            w1o1 = make_float2(RC*(o1.x+o1.y), RC*(o1.y-o1.x));    // (1-i)/sqrt2
            w2o2 = make_float2(o2.y, -o2.x);                       // -i
            w3o3 = make_float2(RC*(o3.y-o3.x), RC*(-o3.x-o3.y));   // -(1+i)/sqrt2
        } else {
            w1o1 = make_float2(RC*(o1.x-o1.y), RC*(o1.y+o1.x));    // (1+i)/sqrt2
            w2o2 = make_float2(-o2.y, o2.x);                       // i
            w3o3 = make_float2(RC*(-o3.x-o3.y), RC*(o3.x-o3.y));   // (-1+i)/sqrt2
        }
        int d = ((j - jm) << 3) + jm;
        out[pidx(d)]      = make_float2(e0.x+o0.x,   e0.y+o0.y);
        out[pidx(d+Ns)]   = make_float2(e1.x+w1o1.x, e1.y+w1o1.y);
        out[pidx(d+2*Ns)] = make_float2(e2.x+w2o2.x, e2.y+w2o2.y);
        out[pidx(d+3*Ns)] = make_float2(e3.x+w3o3.x, e3.y+w3o3.y);
        out[pidx(d+4*Ns)] = make_float2(e0.x-o0.x,   e0.y-o0.y);
        out[pidx(d+5*Ns)] = make_float2(e1.x-w1o1.x, e1.y-w1o1.y);
        out[pidx(d+6*Ns)] = make_float2(e2.x-w2o2.x, e2.y-w2o2.y);
        out[pidx(d+7*Ns)] = make_float2(e3.x-w3o3.x, e3.y-w3o3.y);
    }
}

template<int N, int T, bool INV>
__device__ __forceinline__ void r4stage(const float2* __restrict__ in, float2* __restrict__ out,
                                        const float2* __restrict__ tw, int Ns){
    __syncthreads();
    #pragma unroll
    for (int base = 0; base < N/4; base += T){
        int j = base + (int)threadIdx.x;
        int jm = j & (Ns-1);
        int st = jm * (4096/(Ns*4));
        float2 v0 = in[pidx(j)];
        float2 v1 = in[pidx(j +   N/4)];
        float2 v2 = in[pidx(j + 2*(N/4))];
        float2 v3 = in[pidx(j + 3*(N/4))];
        float2 w1 = tw[st], w2 = tw[2*st], w3 = tw[3*st];
        if (INV){ w1.y=-w1.y; w2.y=-w2.y; w3.y=-w3.y; }
        v1 = cmulf(v1,w1); v2 = cmulf(v2,w2); v3 = cmulf(v3,w3);
        float t0x=v0.x+v2.x, t0y=v0.y+v2.y;
        float t1x=v0.x-v2.x, t1y=v0.y-v2.y;
        float t2x=v1.x+v3.x, t2y=v1.y+v3.y;
        float t3x=v1.x-v3.x, t3y=v1.y-v3.y;
        float2 x0 = make_float2(t0x+t2x, t0y+t2y);
        float2 x2 = make_float2(t0x-t2x, t0y-t2y);
        float2 x1, x3;
        if (!INV){ x1 = make_float2(t1x+t3y, t1y-t3x); x3 = make_float2(t1x-t3y, t1y+t3x); }
        else     { x1 = make_float2(t1x-t3y, t1y+t3x); x3 = make_float2(t1x+t3y, t1y-t3x); }
        int d = ((j - jm) << 2) + jm;
        out[pidx(d)] = x0; out[pidx(d+Ns)] = x1; out[pidx(d+2*Ns)] = x2; out[pidx(d+3*Ns)] = x3;
    }
}

template<int T, bool INV>
__device__ __forceinline__ void fft4096_r8(float2* A, float2* B, const float2* tw){
    r8stage<4096,T,INV>(A,B,tw,1);
    r8stage<4096,T,INV>(B,A,tw,8);
    r8stage<4096,T,INV>(A,B,tw,64);
    r8stage<4096,T,INV>(B,A,tw,512);   // ends in A
    __syncthreads();
}
template<int T, bool INV>
__device__ __forceinline__ void fft2048_r8(float2* A, float2* B, const float2* tw){
    r8stage<2048,T,INV>(A,B,tw,1);
    r8stage<2048,T,INV>(B,A,tw,8);
    r8stage<2048,T,INV>(A,B,tw,64);
    r4stage<2048,T,INV>(B,A,tw,512);   // ends in A
    __syncthreads();
}

// ---------------- kernel C: previous_decode row -> full 4096-bin spectrum ----------------
__global__ __launch_bounds__(512) void kernC(const float* __restrict__ pd, float2* __restrict__ PDF,
                                             const float2* __restrict__ tw){
    __shared__ float2 A[4352], Bb[4352];
    const int tid = threadIdx.x;
    const float* prow = pd + (size_t)blockIdx.x * 2048;
    for (int j = tid; j < 4096; j += 512)
        A[pidx(j)] = (j < 2048) ? make_float2(prow[j], 0.f) : make_float2(0.f, 0.f);
    fft4096_r8<512,false>(A,Bb,tw);
    float2* orow = PDF + (size_t)blockIdx.x * 4096;
    for (int j = tid; j < 4096; j += 512) orow[j] = A[pidx(j)];
}

// ---------------- fused kernel F: per (h, c-quarter): all-2048-point pipeline ----
// Math (same as round 4, restructured for register pressure):
//   K2_even[m] = kf_full[m] (free from Cauchy);
//   K2_odd = fft2048(k * e^{-i pi t/2048}), k = ifft2048(kf_full);
//   x[t<2048] = (ifft2048(pde*K2_even)[t] + e^{+i pi t/2048}*ifft2048(pdo*K2_odd)[t])/4096.
// Final contraction is LINEAR -> accumulate even path and odd path separately,
// never holding both. pde/pdo/dct loaded inline at use (L2-hot), k modulation is
// an in-place own-slot LDS op. Persistent regs: accr/acci = 16 floats (round 4's
// 72-float live set spilled: VGPR=64, 2.3 GB scratch traffic).
__global__ __launch_bounds__(256,4) void kernF(const float2* __restrict__ KFb,
                                               const float2* __restrict__ PDF,
                                               const float* __restrict__ DCT,
                                               const float2* __restrict__ tw,
                                               float* __restrict__ out){
    __shared__ float2 A[2176], Bb[2176];
    const int t = threadIdx.x;
    const int h = blockIdx.x;
    const int cq = blockIdx.y;
    const float4* p0 = (const float4*)(PDF + ((size_t)h)*4096);
    const float4* p1 = (const float4*)(PDF + ((size_t)(256+h))*4096);

    float accr[8], acci[8];
    #pragma unroll
    for (int m=0;m<8;++m){ accr[m]=0.f; acci[m]=0.f; }

    #pragma unroll 1
    for (int cc=0; cc<8; ++cc){
        int c = cq*8 + cc;
        const float2* row = KFb + (size_t)(c*256+h)*1026;
        const float* dct = DCT + (size_t)(h*32 + c) * 2048;

        // ---- Phase E: S_even = pde * kf_full; ifft; accumulate ----
        #pragma unroll
        for (int m=0;m<8;++m){
            int j = t + m*256;
            float2 v;
            if (j <= 1024) v = row[j];
            else { float2 u = row[2048-j]; v = make_float2(u.x, -u.y); }   // Hermitian
            float4 a = p0[j];
            float4 b = p1[j];
            float2 pde = make_float2(a.x - b.y, a.y + b.x);   // P0[2j] + i*P1[2j]
            A[pidx(j)] = cmulf(pde, v);
        }
        fft2048_r8<256,true>(A,Bb,tw);
        #pragma unroll
        for (int m=0;m<8;++m){
            int j = t + m*256;
            float2 xe = A[pidx(j)];
            float d = dct[j] * (1.0f/4096.0f);
            accr[m] = fmaf(xe.x, d, accr[m]);
            acci[m] = fmaf(xe.y, d, acci[m]);
        }
        // ---- Phase O: k = ifft(kf_full); modulate; fft; * pdo; ifft; rotate; acc ----
        #pragma unroll
        for (int m=0;m<8;++m){
            int j = t + m*256;
            float2 v;
            if (j <= 1024) v = row[j];
            else { float2 u = row[2048-j]; v = make_float2(u.x, -u.y); }
            A[pidx(j)] = v;
        }
        fft2048_r8<256,true>(A,Bb,tw);
        #pragma unroll
        for (int m=0;m<8;++m){                 // in-place own-slot: k -> k*e^{-i pi t/2048}
            int j = t + m*256;
            int ji = pidx(j);
            float k = A[ji].x * (1.0f/2048.0f);
            float2 w = tw[j];                  // e^{-2pi i j/4096}
            A[ji] = make_float2(k*w.x, k*w.y);
        }
        fft2048_r8<256,false>(A,Bb,tw);        // K2_odd
        #pragma unroll
        for (int m=0;m<8;++m){                 // in-place own-slot: * pdo
            int j = t + m*256;
            int ji = pidx(j);
            float4 a = p0[j];
            float4 b = p1[j];
            float2 pdo = make_float2(a.z - b.w, a.w + b.z);   // P0[2j+1] + i*P1[2j+1]
            A[ji] = cmulf(pdo, A[ji]);
        }
        fft2048_r8<256,true>(A,Bb,tw);
        #pragma unroll
        for (int m=0;m<8;++m){
            int j = t + m*256;
            float2 w = tw[j];
            float2 e = make_float2(w.x, -w.y);     // e^{+i pi j/2048 half-bin rotation}
            float2 rot = cmulf(e, A[pidx(j)]);
            float d = dct[j] * (1.0f/4096.0f);
            accr[m] = fmaf(rot.x, d, accr[m]);
            acci[m] = fmaf(rot.y, d, acci[m]);
        }
    }
    #pragma unroll
    for (int m=0;m<8;++m){
        int j = t + m*256;
        atomicAdd(&out[((size_t)h)*2048 + j],       accr[m]);   // batch 0 (Re)
        atomicAdd(&out[((size_t)(256+h))*2048 + j], acci[m]);   // batch 1 (Im)
    }
}

extern "C" void kernel_launch(void* const* d_in, const int* in_sizes, int n_in,
                              void* d_out, int out_size, void* d_ws, size_t ws_size,
                              hipStream_t stream) {
    const float* log_dt = (const float*)d_in[0];
    const float* B_ri   = (const float*)d_in[1];
    const float* P_ri   = (const float*)d_in[2];
    const float* C_ri   = (const float*)d_in[3];
    const float* ivw    = (const float*)d_in[4];
    const float* wimag  = (const float*)d_in[5];
    const float* dC     = (const float*)d_in[6];
    const float* pd     = (const float*)d_in[7];

    char* ws = (char*)d_ws;
    float2* TW  = (float2*)(ws + OFF_TW);
    float4* ZT  = (float4*)(ws + OFF_ZT);
    float2* KF  = (float2*)(ws + OFF_KF);
    float2* PDF = (float2*)(ws + OFF_PDF);
    float*  DCT = (float*) (ws + OFF_DCT);
    float* out = (float*)d_out;

    hipMemsetAsync(out, 0, (size_t)out_size * sizeof(float), stream);
    initk<<<16, 256, 0, stream>>>(TW, ZT);
    transpose_dC<<<dim3(256,64), dim3(32,8), 0, stream>>>(dC, DCT);
    cauchy_k<<<dim3(5,256,4), 256, 0, stream>>>(log_dt, B_ri, P_ri, C_ri, ivw, wimag, ZT, KF);
    kernC<<<512, 512, 0, stream>>>(pd, PDF, TW);
    kernF<<<dim3(256,4), 256, 0, stream>>>((const float2*)KF, PDF, DCT, TW, out);
}

// Round 6
// 534.891 us; speedup vs baseline: 2.0785x; 2.0785x over previous
//
#include <hip/hip_runtime.h>
#include <math.h>

// Problem constants (reference: H=256, N=32, S=256, R=1, CCH=32, L=2048, B=2)
#define LF   1025     // L/2+1

// ---- workspace layout (bytes) ----
// TW 32KB @0 | ZT @65536 | KF 8192x1026 float2 @131072 | PDE/PDO @67371008 | DCT @84148224
#define OFF_TW   0
#define OFF_ZT   65536
#define OFF_KF   131072
#define OFF_PDF  67371008
#define OFF_DCT  84148224

__device__ __forceinline__ float2 cmulf(float2 a, float2 b){
    return make_float2(a.x*b.x - a.y*b.y, a.x*b.y + a.y*b.x);
}
// LDS padding: 1 extra float2 per 16 -> breaks power-of-2 bank aliasing of the
// Stockham scatter.
__device__ __forceinline__ int pidx(int i){ return i + (i >> 4); }

// ---------------- init: twiddles + bilinear nodes (fp64 once) ----------------
__global__ void initk(float2* __restrict__ TW, float4* __restrict__ ZT){
    int i = blockIdx.x*256 + threadIdx.x;
    if (i < 4096){
        double th = (-2.0*M_PI) * (double)i / 4096.0;
        TW[i] = make_float2((float)cos(th), (float)sin(th));
    }
    if (i < LF){
        double th = (-2.0*M_PI) * (double)i / 2048.0;
        double cr = cos(th), ci = sin(th);
        double ar = 1.0 + cr, ai = ci;              // 1+w
        double den = ar*ar + ai*ai;
        double nr = 1.0 - cr, ni = -ci;             // 1-w
        double zr = 2.0*(nr*ar + ni*ai)/den;        // z = 2(1-w)/(1+w)
        double zi = 2.0*(ni*ar - nr*ai)/den;
        ZT[i] = make_float4((float)zr, (float)zi, (float)(2.0*ar/den), (float)(-2.0*ai/den));
    }
}

// ---------------- dC (l, h, c) -> DCT (h*32+c, l) ----------------
__global__ void transpose_dC(const float* __restrict__ dC, float* __restrict__ DCT){
    __shared__ float tile[32][33];
    int hc0 = blockIdx.x*32;
    int l0  = blockIdx.y*32;
    int tx = threadIdx.x;
    for (int i = threadIdx.y; i < 32; i += 8)
        tile[i][tx] = dC[(size_t)(l0+i)*8192 + hc0 + tx];
    __syncthreads();
    for (int i = threadIdx.y; i < 32; i += 8)
        DCT[(size_t)(hc0+i)*2048 + l0 + tx] = tile[tx][i];
}

// ---------------- Cauchy + Woodbury -> k_f ---------------- (unchanged, passes)
__global__ __launch_bounds__(256) void cauchy_k(
                         const float* __restrict__ log_dt, const float* __restrict__ B_ri,
                         const float* __restrict__ P_ri, const float* __restrict__ C_ri,
                         const float* __restrict__ ivw, const float* __restrict__ wimag,
                         const float4* __restrict__ ZT, float2* __restrict__ KF)
{
    const int h  = blockIdx.y;
    const int c0 = blockIdx.z * 8;
    const int l  = blockIdx.x*256 + (int)threadIdx.x;
    __shared__ float wre[32], wim[32], bre[32], bim[32], ppre[32], ppim[32];
    __shared__ float cre[8][32], cim[8][32];
    __shared__ float dt_sh;
    if (threadIdx.x < 32){
        int n = threadIdx.x;
        float dt = expf(log_dt[h]);
        wre[n] = -expf(ivw[h*32+n]) * dt;
        wim[n] = wimag[h*32+n] * dt;
        bre[n] = B_ri[(h*32+n)*2+0];
        bim[n] = B_ri[(h*32+n)*2+1];
        ppre[n] = P_ri[(h*32+n)*2+0];
        ppim[n] = P_ri[(h*32+n)*2+1];
        if (n == 0) dt_sh = dt;
    }
    {
        int i = threadIdx.x;
        int cc = i >> 5, n = i & 31;
        size_t base = (((size_t)(c0+cc)*256 + h)*32 + n)*2;
        cre[cc][n] = C_ri[base+0];
        cim[cc][n] = C_ri[base+1];
    }
    __syncthreads();
    if (l >= LF) return;

    float4 zt = ZT[l];
    const float zx = zt.x, zy = zt.y;
    float r0x[9], r0y[9], r1x[9], r1y[9];
    #pragma unroll
    for (int j=0;j<9;++j){ r0x[j]=0.f; r0y[j]=0.f; r1x[j]=0.f; r1y[j]=0.f; }

    #pragma unroll 1
    for (int n=0; n<32; ++n){
        float wr = wre[n], wi = wim[n];
        float dx = zx - wr;
        float dy = zy - wi;
        float ey = zy + wi;
        float ip = 1.0f/(dx*dx + dy*dy);
        float im = 1.0f/(dx*dx + ey*ey);
        float cpx = dx*ip, cpy = -dy*ip;
        float cmx = dx*im, cmy = -ey*im;
        float br = bre[n], bi = bim[n];
        float t0x = br*cpx - bi*cpy, t0y = br*cpy + bi*cpx;
        float t1x = br*cmx + bi*cmy, t1y = br*cmy - bi*cmx;
        float pr = ppre[n], pi = ppim[n];
        float t2x = pr*cpx - pi*cpy, t2y = pr*cpy + pi*cpx;
        float t3x = pr*cmx + pi*cmy, t3y = pr*cmy - pi*cmx;
        float u0 = t0x+t1x, v0 = t1y-t0y, s0 = t0y+t1y, q0 = t0x-t1x;
        float u1 = t2x+t3x, v1 = t3y-t2y, s1 = t2y+t3y, q1 = t2x-t3x;
        #pragma unroll
        for (int j=0;j<8;++j){
            float a = cre[j][n], b = cim[j][n];
            r0x[j] = fmaf(a,u0, fmaf(b,v0, r0x[j]));
            r0y[j] = fmaf(a,s0, fmaf(b,q0, r0y[j]));
            r1x[j] = fmaf(a,u1, fmaf(b,v1, r1x[j]));
            r1y[j] = fmaf(a,s1, fmaf(b,q1, r1y[j]));
        }
        r0x[8] = fmaf(pr,u0, fmaf(-pi,v0, r0x[8]));
        r0y[8] = fmaf(pr,s0, fmaf(-pi,q0, r0y[8]));
        r1x[8] = fmaf(pr,u1, fmaf(-pi,v1, r1x[8]));
        r1y[8] = fmaf(pr,s1, fmaf(-pi,q1, r1y[8]));
    }

    float dt = dt_sh;
    #pragma unroll
    for (int j=0;j<9;++j){ r0x[j]*=dt; r0y[j]*=dt; r1x[j]*=dt; r1y[j]*=dt; }
    float drr = 1.0f + r1x[8], dii = r1y[8];
    float idn = 1.0f/(drr*drr + dii*dii);
    float gx = (r0x[8]*drr + r0y[8]*dii)*idn;
    float gy = (r0y[8]*drr - r0x[8]*dii)*idn;
    float tfx = zt.z, tfy = zt.w;
    #pragma unroll
    for (int j=0;j<8;++j){
        float kr = r0x[j] - (gx*r1x[j] - gy*r1y[j]);
        float ki = r0y[j] - (gx*r1y[j] + gy*r1x[j]);
        KF[((size_t)((c0+j)*256+h))*1026 + l] = make_float2(kr*tfx - ki*tfy, kr*tfy + ki*tfx);
    }
}

// ---------------- Stockham stages, radix-8 / radix-4, padded LDS ----------------
template<int N, int T, bool INV>
__device__ __forceinline__ void r8stage(const float2* __restrict__ in, float2* __restrict__ out,
                                        const float2* __restrict__ tw, int Ns){
    __syncthreads();
    #pragma unroll
    for (int base = 0; base < N/8; base += T){
        int j = base + (int)threadIdx.x;
        int jm = j & (Ns-1);
        int st = jm * (4096/(Ns*8));
        float2 v[8];
        #pragma unroll
        for (int m=0;m<8;++m) v[m] = in[pidx(j + m*(N/8))];
        #pragma unroll
        for (int m=1;m<8;++m){
            float2 w = tw[m*st];
            if (INV) w.y = -w.y;
            v[m] = cmulf(v[m], w);
        }
        float2 e0,e1,e2,e3,o0,o1,o2,o3;
        {   // DFT4 of v0,v2,v4,v6
            float t0x=v[0].x+v[4].x, t0y=v[0].y+v[4].y;
            float t1x=v[0].x-v[4].x, t1y=v[0].y-v[4].y;
            float t2x=v[2].x+v[6].x, t2y=v[2].y+v[6].y;
            float t3x=v[2].x-v[6].x, t3y=v[2].y-v[6].y;
            e0 = make_float2(t0x+t2x, t0y+t2y);
            e2 = make_float2(t0x-t2x, t0y-t2y);
            if (!INV){ e1 = make_float2(t1x+t3y, t1y-t3x); e3 = make_float2(t1x-t3y, t1y+t3x); }
            else     { e1 = make_float2(t1x-t3y, t1y+t3x); e3 = make_float2(t1x+t3y, t1y-t3x); }
        }
        {   // DFT4 of v1,v3,v5,v7
            float t0x=v[1].x+v[5].x, t0y=v[1].y+v[5].y;
            float t1x=v[1].x-v[5].x, t1y=v[1].y-v[5].y;
            float t2x=v[3].x+v[7].x, t2y=v[3].y+v[7].y;
            float t3x=v[3].x-v[7].x, t3y=v[3].y-v[7].y;
            o0 = make_float2(t0x+t2x, t0y+t2y);
            o2 = make_float2(t0x-t2x, t0y-t2y);
            if (!INV){ o1 = make_float2(t1x+t3y, t1y-t3x); o3 = make_float2(t1x-t3y, t1y+t3x); }
            else     { o1 = make_float2(t1x-t3y, t1y+t3x); o3 = make_float2(t1x+t3y, t1y-t3x); }
        }
        const float RC = 0.70710678118654752f;
        float2 w1o1, w2o2, w3o3;
        if (!INV){
            w1o1 = make_float2(RC*(o1.x+o1.y), RC*(o1.y-o1.x));    // (1-i)/sqrt2
            w2o2 = make_float2(o2.y, -o2.x);                       // -i
            w3o3 = make_float2(RC*(o3.y-o3.x), RC*(-o3.x-o3.y));   // -(1+i)/sqrt2
        } else {
            w1o1 = make_float2(RC*(o1.x-o1.y), RC*(o1.y+o1.x));    // (1+i)/sqrt2
            w2o2 = make_float2(-o2.y, o2.x);                       // i
            w3o3 = make_float2(RC*(-o3.x-o3.y), RC*(o3.x-o3.y));   // (-1+i)/sqrt2
        }
        int d = ((j - jm) << 3) + jm;
        out[pidx(d)]      = make_float2(e0.x+o0.x,   e0.y+o0.y);
        out[pidx(d+Ns)]   = make_float2(e1.x+w1o1.x, e1.y+w1o1.y);
        out[pidx(d+2*Ns)] = make_float2(e2.x+w2o2.x, e2.y+w2o2.y);
        out[pidx(d+3*Ns)] = make_float2(e3.x+w3o3.x, e3.y+w3o3.y);
        out[pidx(d+4*Ns)] = make_float2(e0.x-o0.x,   e0.y-o0.y);
        out[pidx(d+5*Ns)] = make_float2(e1.x-w1o1.x, e1.y-w1o1.y);
        out[pidx(d+6*Ns)] = make_float2(e2.x-w2o2.x, e2.y-w2o2.y);
        out[pidx(d+7*Ns)] = make_float2(e3.x-w3o3.x, e3.y-w3o3.y);
    }
}

template<int N, int T, bool INV>
__device__ __forceinline__ void r4stage(const float2* __restrict__ in, float2* __restrict__ out,
                                        const float2* __restrict__ tw, int Ns){
    __syncthreads();
    #pragma unroll
    for (int base = 0; base < N/4; base += T){
        int j = base + (int)threadIdx.x;
        int jm = j & (Ns-1);
        int st = jm * (4096/(Ns*4));
        float2 v0 = in[pidx(j)];
        float2 v1 = in[pidx(j +   N/4)];
        float2 v2 = in[pidx(j + 2*(N/4))];
        float2 v3 = in[pidx(j + 3*(N/4))];
        float2 w1 = tw[st], w2 = tw[2*st], w3 = tw[3*st];
        if (INV){ w1.y=-w1.y; w2.y=-w2.y; w3.y=-w3.y; }
        v1 = cmulf(v1,w1); v2 = cmulf(v2,w2); v3 = cmulf(v3,w3);
        float t0x=v0.x+v2.x, t0y=v0.y+v2.y;
        float t1x=v0.x-v2.x, t1y=v0.y-v2.y;
        float t2x=v1.x+v3.x, t2y=v1.y+v3.y;
        float t3x=v1.x-v3.x, t3y=v1.y-v3.y;
        float2 x0 = make_float2(t0x+t2x, t0y+t2y);
        float2 x2 = make_float2(t0x-t2x, t0y-t2y);
        float2 x1, x3;
        if (!INV){ x1 = make_float2(t1x+t3y, t1y-t3x); x3 = make_float2(t1x-t3y, t1y+t3x); }
        else     { x1 = make_float2(t1x-t3y, t1y+t3x); x3 = make_float2(t1x+t3y, t1y-t3x); }
        int d = ((j - jm) << 2) + jm;
        out[pidx(d)] = x0; out[pidx(d+Ns)] = x1; out[pidx(d+2*Ns)] = x2; out[pidx(d+3*Ns)] = x3;
    }
}

template<int T, bool INV>
__device__ __forceinline__ void fft2048_r8(float2* A, float2* B, const float2* tw){
    r8stage<2048,T,INV>(A,B,tw,1);
    r8stage<2048,T,INV>(B,A,tw,8);
    r8stage<2048,T,INV>(A,B,tw,64);
    r4stage<2048,T,INV>(B,A,tw,512);   // ends in A
    __syncthreads();
}

// ---------------- kernel C2: pd rows -> packed even/odd 4096-bin spectra ---------
// Z = pd_b0 + i*pd_b1 (per h). PDE[h][j] = fft2048(Z)[j]      = P0[2j]  +i*P1[2j]
//                      PDO[h][j] = fft2048(Z*e^{-2pi i t/4096})[j] = P0[2j+1]+i*P1[2j+1]
// (even bins of zero-padded 4096-DFT == cyclic 2048-DFT; odd bins == modulated.)
__global__ __launch_bounds__(256) void kernC2(const float* __restrict__ pd,
                                              float2* __restrict__ PDE, float2* __restrict__ PDO,
                                              const float2* __restrict__ tw){
    __shared__ float2 A[2176], Bb[2176];
    const int t = threadIdx.x;
    const int h = blockIdx.x;
    const float* p0 = pd + (size_t)h * 2048;
    const float* p1 = pd + (size_t)(256 + h) * 2048;
    for (int m = 0; m < 8; ++m){
        int j = t + m*256;
        A[pidx(j)] = make_float2(p0[j], p1[j]);
    }
    fft2048_r8<256,false>(A,Bb,tw);
    float2* oe = PDE + (size_t)h * 2048;
    for (int m = 0; m < 8; ++m){
        int j = t + m*256;
        oe[j] = A[pidx(j)];
    }
    for (int m = 0; m < 8; ++m){
        int j = t + m*256;
        float2 z = make_float2(p0[j], p1[j]);    // L1/L2-hot re-read
        A[pidx(j)] = cmulf(tw[j], z);            // * e^{-2pi i j/4096}
    }
    fft2048_r8<256,false>(A,Bb,tw);
    float2* oo = PDO + (size_t)h * 2048;
    for (int m = 0; m < 8; ++m){
        int j = t + m*256;
        oo[j] = A[pidx(j)];
    }
}

// ---------------- fused kernel F: per (h, c-half): all-2048-point pipeline ----
// Math (identical to round 5, which passed):
//   K2_even = kf_full (free from Cauchy); K2_odd = fft2048(k*e^{-i pi t/2048}),
//   k = ifft2048(kf_full)/2048;
//   x = (ifft_u(PDE*K2_even) + e^{+2pi i t/4096}*ifft_u(PDO*K2_odd))/4096.
// Round-5 failure mode fixed: PDE/PDO staged in LDS ONCE per block (round 5
// re-read 64 KB of PDF per channel per phase from HBM -> 1 GB + register-burst
// spill). LDS 67.6 KB -> 2 blocks/CU; grid 512 = fully resident; 256-VGPR cap.
__global__ __launch_bounds__(256,2) void kernF(const float2* __restrict__ KFb,
                                               const float2* __restrict__ PDE,
                                               const float2* __restrict__ PDO,
                                               const float* __restrict__ DCT,
                                               const float2* __restrict__ tw,
                                               float* __restrict__ out){
    __shared__ float2 A[2176], Bb[2176];
    __shared__ float2 pde_s[2048], pdo_s[2048];
    const int t = threadIdx.x;
    const int h = blockIdx.x;
    const int cq = blockIdx.y;                 // 0..1, 16 channels each
    {
        const float2* pe = PDE + (size_t)h * 2048;
        const float2* po = PDO + (size_t)h * 2048;
        #pragma unroll
        for (int m=0;m<8;++m){
            int j = t + m*256;
            pde_s[j] = pe[j];
            pdo_s[j] = po[j];
        }
    }
    float accr[8], acci[8];
    #pragma unroll
    for (int m=0;m<8;++m){ accr[m]=0.f; acci[m]=0.f; }
    __syncthreads();                            // pde_s/pdo_s visible to all

    #pragma unroll 1
    for (int cc=0; cc<16; ++cc){
        int c = cq*16 + cc;
        const float2* row = KFb + (size_t)(c*256+h)*1026;
        float dcv[8];
        {
            const float* dct = DCT + (size_t)(h*32 + c) * 2048;
            #pragma unroll
            for (int m=0;m<8;++m) dcv[m] = dct[t + m*256] * (1.0f/4096.0f);
        }
        // ---- Phase E: S_even = pde * kf_full; ifft; accumulate ----
        #pragma unroll
        for (int m=0;m<8;++m){
            int j = t + m*256;
            float2 v;
            if (j <= 1024) v = row[j];
            else { float2 u = row[2048-j]; v = make_float2(u.x, -u.y); }   // Hermitian
            A[pidx(j)] = cmulf(pde_s[j], v);
        }
        fft2048_r8<256,true>(A,Bb,tw);
        #pragma unroll
        for (int m=0;m<8;++m){
            int j = t + m*256;
            float2 xe = A[pidx(j)];
            accr[m] = fmaf(xe.x, dcv[m], accr[m]);
            acci[m] = fmaf(xe.y, dcv[m], acci[m]);
        }
        // ---- Phase O: k = ifft(kf); modulate; fft; * pdo; ifft; rotate; acc ----
        #pragma unroll
        for (int m=0;m<8;++m){
            int j = t + m*256;
            float2 v;
            if (j <= 1024) v = row[j];               // L2-hot re-read
            else { float2 u = row[2048-j]; v = make_float2(u.x, -u.y); }
            A[pidx(j)] = v;
        }
        fft2048_r8<256,true>(A,Bb,tw);
        #pragma unroll
        for (int m=0;m<8;++m){                       // in-place own-slot modulate
            int j = t + m*256;
            int ji = pidx(j);
            float k = A[ji].x * (1.0f/2048.0f);
            float2 w = tw[j];                        // e^{-2pi i j/4096}
            A[ji] = make_float2(k*w.x, k*w.y);
        }
        fft2048_r8<256,false>(A,Bb,tw);              // K2_odd
        #pragma unroll
        for (int m=0;m<8;++m){                       // in-place own-slot * pdo
            int j = t + m*256;
            int ji = pidx(j);
            A[ji] = cmulf(pdo_s[j], A[ji]);
        }
        fft2048_r8<256,true>(A,Bb,tw);
        #pragma unroll
        for (int m=0;m<8;++m){
            int j = t + m*256;
            float2 w = tw[j];
            float2 e = make_float2(w.x, -w.y);       // e^{+2pi i j/4096}
            float2 rot = cmulf(e, A[pidx(j)]);
            accr[m] = fmaf(rot.x, dcv[m], accr[m]);
            acci[m] = fmaf(rot.y, dcv[m], acci[m]);
        }
    }
    #pragma unroll
    for (int m=0;m<8;++m){
        int j = t + m*256;
        atomicAdd(&out[((size_t)h)*2048 + j],       accr[m]);   // batch 0 (Re)
        atomicAdd(&out[((size_t)(256+h))*2048 + j], acci[m]);   // batch 1 (Im)
    }
}

extern "C" void kernel_launch(void* const* d_in, const int* in_sizes, int n_in,
                              void* d_out, int out_size, void* d_ws, size_t ws_size,
                              hipStream_t stream) {
    const float* log_dt = (const float*)d_in[0];
    const float* B_ri   = (const float*)d_in[1];
    const float* P_ri   = (const float*)d_in[2];
    const float* C_ri   = (const float*)d_in[3];
    const float* ivw    = (const float*)d_in[4];
    const float* wimag  = (const float*)d_in[5];
    const float* dC     = (const float*)d_in[6];
    const float* pd     = (const float*)d_in[7];

    char* ws = (char*)d_ws;
    float2* TW  = (float2*)(ws + OFF_TW);
    float4* ZT  = (float4*)(ws + OFF_ZT);
    float2* KF  = (float2*)(ws + OFF_KF);
    float2* PDE = (float2*)(ws + OFF_PDF);
    float2* PDO = (float2*)(ws + OFF_PDF + 256*2048*sizeof(float2));
    float*  DCT = (float*) (ws + OFF_DCT);
    float* out = (float*)d_out;

    hipMemsetAsync(out, 0, (size_t)out_size * sizeof(float), stream);
    initk<<<16, 256, 0, stream>>>(TW, ZT);
    transpose_dC<<<dim3(256,64), dim3(32,8), 0, stream>>>(dC, DCT);
    cauchy_k<<<dim3(5,256,4), 256, 0, stream>>>(log_dt, B_ri, P_ri, C_ri, ivw, wimag, ZT, KF);
    kernC2<<<256, 256, 0, stream>>>(pd, PDE, PDO, TW);
    kernF<<<dim3(256,2), 256, 0, stream>>>((const float2*)KF, PDE, PDO, DCT, TW, out);
}